// Round 8
// baseline (167.367 us; speedup 1.0000x reference)
//
#include <hip/hip_runtime.h>

#define HD 32
#define NHEADS 12
#define HH 56
#define WW 56
#define NN (HH * WW)
#define BB 8
#define CC (HD * NHEADS)
#define SCALE 0.17677669529663689f

// Round-8: identical structure to round-7 (center-tap loads + full q/k/v
// register prefetch + one LDS quarter-exchange), with the 192 neighbor
// __shfl_up/down(1) (ds_bpermute, ~120cy LDS round-trips -- the r7 stall
// source) replaced by DPP whole-wave shifts on the VALU:
//   wave_shr:1 (0x138): lane i <- lane i-1  (== shfl_up 1)
//   wave_shl:1 (0x130): lane i <- lane i+1  (== shfl_down 1)
// bound_ctrl=1 -> edge lanes read 0, which matches the unfold zero-padding
// masks already in place (mlo/mhi/rm and the inactive tx>=56 stores).
__device__ __forceinline__ float dpp_up1(float x) {   // lane i <- lane i-1; lane0 <- 0
    return __int_as_float(
        __builtin_amdgcn_update_dpp(0, __float_as_int(x), 0x138, 0xF, 0xF, true));
}
__device__ __forceinline__ float dpp_dn1(float x) {   // lane i <- lane i+1; lane63 <- 0
    return __int_as_float(
        __builtin_amdgcn_update_dpp(0, __float_as_int(x), 0x130, 0xF, 0xF, true));
}

__global__ __launch_bounds__(256) void dilate_attn_kernel(
    const float* __restrict__ q,
    const float* __restrict__ k,
    const float* __restrict__ v,
    float* __restrict__ out)
{
    const int tx = threadIdx.x;            // 0..63 (pair within 2-row stripe)
    const int qc = threadIdx.y;            // 0..3 channel quarter
    const int bh = blockIdx.y;
    const int b = bh / NHEADS;
    const int head = bh - b * NHEADS;

    const int n0r = blockIdx.x * 112 + 2 * tx;
    const int n0 = (n0r <= NN - 2) ? n0r : NN - 2;   // clamp idle lanes
    const bool active = (tx < 56);

    const int y  = n0 / WW;
    const int x0 = n0 - y * WW;            // even; block base is row-aligned
    const float mlo = (x0 == 0)      ? 0.f : 1.f;
    const float mhi = (x0 == WW - 2) ? 0.f : 1.f;

    const int base0 = (b * CC + head * HD + qc * 8) * NN;

    __shared__ float2 part[4][64][9];      // 18432 B logit exchange

    // ---- prefetch: 56 independent float2 loads, no branches ----
    float2 qv[8];
#pragma unroll
    for (int d = 0; d < 8; ++d)
        qv[d] = *reinterpret_cast<const float2*>(q + base0 + d * NN + n0);

    float rm[3]; int rb[3];
#pragma unroll
    for (int r = 0; r < 3; ++r) {
        const int ny = y + (r - 1) * 2;
        rm[r] = ((unsigned)ny < HH) ? 1.f : 0.f;
        const int nyc = ny < 0 ? 0 : (ny > HH - 1 ? HH - 1 : ny);
        rb[r] = base0 + nyc * WW + x0;
    }

    float2 km[3][8];
#pragma unroll
    for (int r = 0; r < 3; ++r)
#pragma unroll
        for (int d = 0; d < 8; ++d)
            km[r][d] = *reinterpret_cast<const float2*>(k + rb[r] + d * NN);

    float2 vm[3][8];
#pragma unroll
    for (int r = 0; r < 3; ++r)
#pragma unroll
        for (int d = 0; d < 8; ++d)
            vm[r][d] = *reinterpret_cast<const float2*>(v + rb[r] + d * NN);

    // ---- QK: center tap local, side taps via DPP wave shifts ----
    float lg[9][2];
#pragma unroll
    for (int r = 0; r < 3; ++r) {
        float s0x = 0.f, s0y = 0.f, s1x = 0.f, s1y = 0.f, s2x = 0.f, s2y = 0.f;
#pragma unroll
        for (int d = 0; d < 8; ++d) {
            const float2 w1 = km[r][d];
            const float w0x = dpp_up1(w1.x);
            const float w0y = dpp_up1(w1.y);
            const float w2x = dpp_dn1(w1.x);
            const float w2y = dpp_dn1(w1.y);
            s0x = fmaf(qv[d].x, w0x, s0x);  s0y = fmaf(qv[d].y, w0y, s0y);
            s1x = fmaf(qv[d].x, w1.x, s1x); s1y = fmaf(qv[d].y, w1.y, s1y);
            s2x = fmaf(qv[d].x, w2x, s2x);  s2y = fmaf(qv[d].y, w2y, s2y);
        }
        const float m0 = rm[r] * mlo, m2 = rm[r] * mhi;
        lg[r * 3 + 0][0] = s0x * m0;    lg[r * 3 + 0][1] = s0y * m0;
        lg[r * 3 + 1][0] = s1x * rm[r]; lg[r * 3 + 1][1] = s1y * rm[r];
        lg[r * 3 + 2][0] = s2x * m2;    lg[r * 3 + 2][1] = s2y * m2;
    }

    // ---- combine quarters via LDS (one barrier) ----
#pragma unroll
    for (int t = 0; t < 9; ++t) part[qc][tx][t] = make_float2(lg[t][0], lg[t][1]);
    __syncthreads();
#pragma unroll
    for (int o = 1; o < 4; ++o) {
        const int oq = (qc + o) & 3;
#pragma unroll
        for (int t = 0; t < 9; ++t) {
            const float2 p = part[oq][tx][t];
            lg[t][0] += p.x; lg[t][1] += p.y;
        }
    }

    // ---- softmax over 9 taps (dup per quarter; cheap) ----
#pragma unroll
    for (int j = 0; j < 2; ++j) {
        float m = lg[0][j] * SCALE;
#pragma unroll
        for (int t = 0; t < 9; ++t) { lg[t][j] *= SCALE; m = fmaxf(m, lg[t][j]); }
        float s = 0.f;
#pragma unroll
        for (int t = 0; t < 9; ++t) { const float e = __expf(lg[t][j] - m); lg[t][j] = e; s += e; }
        const float inv = 1.f / s;
#pragma unroll
        for (int t = 0; t < 9; ++t) lg[t][j] *= inv;
    }
    // re-mask: invalid taps have nonzero softmax weight but v==0 in the ref
#pragma unroll
    for (int r = 0; r < 3; ++r) {
        const float m0 = rm[r] * mlo, m2 = rm[r] * mhi;
        lg[r * 3 + 0][0] *= m0;    lg[r * 3 + 0][1] *= m0;
        lg[r * 3 + 1][0] *= rm[r]; lg[r * 3 + 1][1] *= rm[r];
        lg[r * 3 + 2][0] *= m2;    lg[r * 3 + 2][1] *= m2;
    }

    // ---- PV: center tap local, side taps via DPP wave shifts ----
    float acc[8][2];
#pragma unroll
    for (int d = 0; d < 8; ++d) { acc[d][0] = 0.f; acc[d][1] = 0.f; }
#pragma unroll
    for (int r = 0; r < 3; ++r) {
        const float g0x = lg[r * 3 + 0][0], g0y = lg[r * 3 + 0][1];
        const float g1x = lg[r * 3 + 1][0], g1y = lg[r * 3 + 1][1];
        const float g2x = lg[r * 3 + 2][0], g2y = lg[r * 3 + 2][1];
#pragma unroll
        for (int d = 0; d < 8; ++d) {
            const float2 u1 = vm[r][d];
            const float u0x = dpp_up1(u1.x);
            const float u0y = dpp_up1(u1.y);
            const float u2x = dpp_dn1(u1.x);
            const float u2y = dpp_dn1(u1.y);
            acc[d][0] = fmaf(g0x, u0x, acc[d][0]);  acc[d][1] = fmaf(g0y, u0y, acc[d][1]);
            acc[d][0] = fmaf(g1x, u1.x, acc[d][0]); acc[d][1] = fmaf(g1y, u1.y, acc[d][1]);
            acc[d][0] = fmaf(g2x, u2x, acc[d][0]);  acc[d][1] = fmaf(g2y, u2y, acc[d][1]);
        }
    }

    // ---- store: out[b, y, x0+j, head*32 + qc*8 + 0..7] ----
    if (active) {
#pragma unroll
        for (int j = 0; j < 2; ++j) {
            float* ob = out + ((b * HH + y) * WW + (x0 + j)) * CC + head * HD + qc * 8;
            *reinterpret_cast<float4*>(ob)     = make_float4(acc[0][j], acc[1][j], acc[2][j], acc[3][j]);
            *reinterpret_cast<float4*>(ob + 4) = make_float4(acc[4][j], acc[5][j], acc[6][j], acc[7][j]);
        }
    }
}

extern "C" void kernel_launch(void* const* d_in, const int* in_sizes, int n_in,
                              void* d_out, int out_size, void* d_ws, size_t ws_size,
                              hipStream_t stream) {
    const float* q = (const float*)d_in[0];
    const float* k = (const float*)d_in[1];
    const float* v = (const float*)d_in[2];
    float* out = (float*)d_out;

    dim3 block(64, 4);
    dim3 grid(NN / 112, BB * NHEADS);   // 28 x 96; 28*112 = 3136 = NN exact
    dilate_attn_kernel<<<grid, block, 0, stream>>>(q, k, v, out);
}